// Round 20
// baseline (216.233 us; speedup 1.0000x reference)
//
#include <hip/hip_runtime.h>
#include <hip/hip_bf16.h>
#include <math.h>

#define BB   64
#define TT   1000
#define DEC  1024
#define ENCD 512
#define ATT  128
#define FILT 32
#define KSZ  31
#define PADW 15
#define BT   32    // t-tile per block (full-K slab resident)
#define NTL  32    // tiles per b
#define XWN  64    // x-window alloc (62 used)

typedef __attribute__((ext_vector_type(8))) short bf16x8;
typedef __attribute__((ext_vector_type(4))) float f32x4;

static __device__ __forceinline__ ushort f2bf(float f) {
    union { float f; unsigned u; } v; v.f = f;
    unsigned r = (v.u + 0x7FFFu + ((v.u >> 16) & 1u)) >> 16;   // RNE
    return (ushort)r;
}

static __device__ __forceinline__ bf16x8 cvt8(float4 lo, float4 hi) {
    union { __hip_bfloat162 h[4]; bf16x8 v; } u;
    u.h[0] = __float22bfloat162_rn(make_float2(lo.x, lo.y));
    u.h[1] = __float22bfloat162_rn(make_float2(lo.z, lo.w));
    u.h[2] = __float22bfloat162_rn(make_float2(hi.x, hi.y));
    u.h[3] = __float22bfloat162_rn(make_float2(hi.z, hi.w));
    return u.v;
}

static __device__ __forceinline__ float fast_tanh(float x) {
    float e = __expf(2.f * x);
    return 1.f - 2.f * __builtin_amdgcn_rcpf(e + 1.f);
}

// async global->LDS, 16B per lane; LDS dest = wave-uniform base + lane*16
static __device__ __forceinline__ void gl2lds16(const void* g, void* l) {
    __builtin_amdgcn_global_load_lds(
        (const __attribute__((address_space(1))) unsigned*)g,
        (__attribute__((address_space(3))) unsigned*)l, 16, 0, 0);
}

// ---------------- K0: pack key_w + W2 (frag-major), M = sum|v|, query GEMV ----
__global__ __launch_bounds__(256) void k_prep(const float* __restrict__ kw,
                                              const float* __restrict__ cw,
                                              const float* __restrict__ lpw,
                                              const float* __restrict__ dh,
                                              const float* __restrict__ qw,
                                              const float* __restrict__ vw,
                                              ushort* __restrict__ kwbF,
                                              float* __restrict__ q,
                                              float* __restrict__ Mbuf,
                                              int* __restrict__ cnt) {
    __shared__ float qred[128];
    if (blockIdx.x < 32) {
        int idx = blockIdx.x * 256 + threadIdx.x;     // 0..8191
        int l  = idx & 63;
        int n  = (idx >> 6) & 7;
        int ks = (idx >> 9) & 1;
        int c  = idx >> 10;
        int a  = n * 16 + (l & 15);
        int k0 = c * 64 + ks * 32 + (l >> 4) * 8;
        ushort u[8];
        #pragma unroll
        for (int j = 0; j < 8; ++j) u[j] = f2bf(kw[a * ENCD + k0 + j]);
        *(uint4*)&kwbF[(size_t)idx * 8] = *(const uint4*)u;
    } else if (blockIdx.x < 36) {
        // W2[c][k][a] = sum_f conv_w[f][c][k] * loc_proj_w[a][f];  k==31 row = 0
        int idx = (blockIdx.x - 32) * 256 + threadIdx.x;   // 0..1023
        int l  = idx & 63;
        int n  = (idx >> 6) & 7;
        int ks = (idx >> 9) & 1;                      // conv input channel
        int a  = n * 16 + (l & 15);
        int s  = l >> 4;
        ushort u[8];
        #pragma unroll
        for (int j = 0; j < 8; ++j) {
            int k = s * 8 + j;
            float v = 0.f;
            if (k < KSZ) {
                #pragma unroll
                for (int f = 0; f < FILT; ++f)
                    v += cw[(f * 2 + ks) * KSZ + k] * lpw[a * FILT + f];
            }
            u[j] = f2bf(v);
        }
        *(uint4*)&kwbF[(size_t)(((16 + ks) * 8 + n) * 64 + l) * 8] = *(const uint4*)u;
    } else if (blockIdx.x == 36) {
        if (threadIdx.x < 64) {
            float m0 = fabsf(vw[threadIdx.x]) + fabsf(vw[threadIdx.x + 64]);
            #pragma unroll
            for (int off = 1; off < 64; off <<= 1) m0 += __shfl_xor(m0, off, 64);
            if (threadIdx.x == 0) Mbuf[0] = m0;
        }
        if (threadIdx.x < BB) cnt[threadIdx.x] = 0;   // arrival counters
    } else {
        // query GEMV, one block per b, 128 a x 2-way k-split
        int b  = blockIdx.x - 37;
        int a  = threadIdx.x & 127;
        int kh = threadIdx.x >> 7;
        const float* dhb = dh + b * DEC + kh * 512;
        const float* qwa = qw + a * DEC + kh * 512;
        float s = 0.f;
        #pragma unroll 4
        for (int k = 0; k < 512; k += 4) {
            float4 x = *(const float4*)&dhb[k];
            float4 w = *(const float4*)&qwa[k];
            s += x.x * w.x + x.y * w.y + x.z * w.z + x.w * w.w;
        }
        if (kh == 1) qred[a] = s;
        __syncthreads();
        if (kh == 0) q[b * ATT + a] = s + qred[a];
    }
}

// ------- K3: contiguous-stream slab GEMM K=576 -> expE + ctx, FUSED reduce ----
// r19 structure (best). NEW: last-block-per-b tail performs the cross-tile
// reduction (ps-sum, ctx, wout) -- removes the third kernel + its launch.
__global__ __launch_bounds__(256) void k_energies(
    const float* __restrict__ enc, const float* __restrict__ pw,
    const float* __restrict__ pwc, const unsigned char* __restrict__ mask,
    const ushort* __restrict__ kwbF, const float* __restrict__ vw,
    const float* __restrict__ q, const float* __restrict__ Mbuf,
    float* __restrict__ expE, float* __restrict__ pctx,
    float* __restrict__ ps, int* __restrict__ cnt,
    float* __restrict__ ctx, float* __restrict__ wout)
{
    __shared__ __align__(16) float As[BT * ENCD];   // 64 KB slab, unit-swizzled
    __shared__ __align__(16) float xw[2][XWN];
    __shared__ float pequad[4][BT];
    __shared__ float sExp[BT];
    __shared__ int lastFlag;

    const int b    = blockIdx.x;
    const int tile = blockIdx.y;
    const int t0   = tile * BT;
    const int tid  = threadIdx.x;
    const int w    = tid >> 6;       // 4 waves; wave owns a-cols [w*32, w*32+32)
    const int l    = tid & 63;
    const int r    = l & 15;
    const int sl   = l >> 4;

    const float* encb = enc + (size_t)b * TT * ENCD;

    // ---- xw staging FIRST (oldest VMEM ops; waves 2,3 have none) ----
    for (int i = tid; i < 2 * XWN; i += 256) {
        int c  = i / XWN;
        int ii = i - c * XWN;
        int tg = t0 + ii - PADW;
        const float* src = c ? pwc : pw;
        xw[c][ii] = (ii < BT + KSZ - 1 && tg >= 0 && tg < TT) ? src[b * TT + tg] : 0.f;
    }
    __builtin_amdgcn_sched_barrier(0);

    // ---- h0: first halves of this wave's 8 rows (contiguous 1 KB streams) ----
    #pragma unroll
    for (int j = 0; j < 8; ++j) {
        int rl = w * 8 + j;
        int rg = t0 + rl; if (rg >= TT) rg = TT - 1;
        const float* src = encb + (size_t)rg * ENCD + (size_t)(sl * 16 + (r ^ (rl & 15))) * 4;
        gl2lds16(src, (char*)As + rl * 2048);
    }
    __builtin_amdgcn_sched_barrier(0);

    // ---- B for stage 1 (chunks 0..3 + feat 8) -> named reg sets ----
    uint4 bA[2][2], bB[2][2], bC[2][2], bD[2][2], bW[2][2];
    auto loadB = [&](uint4 (&dst)[2][2], int c) {
        #pragma unroll
        for (int ks = 0; ks < 2; ++ks)
            #pragma unroll
            for (int nn = 0; nn < 2; ++nn)
                dst[ks][nn] = *(const uint4*)&kwbF[(size_t)(((c * 2 + ks) * 8 + w * 2 + nn) * 64 + l) * 8];
    };
    loadB(bA, 0); loadB(bB, 1); loadB(bC, 2); loadB(bD, 3); loadB(bW, 8);
    __builtin_amdgcn_sched_barrier(0);

    // ---- h1: second halves (stay in flight across stage 1) ----
    #pragma unroll
    for (int j = 0; j < 8; ++j) {
        int rl = w * 8 + j;
        int rg = t0 + rl; if (rg >= TT) rg = TT - 1;
        const float* src = encb + (size_t)rg * ENCD + 256 + (size_t)(sl * 16 + (r ^ (rl & 15))) * 4;
        gl2lds16(src, (char*)As + rl * 2048 + 1024);
    }
    __builtin_amdgcn_sched_barrier(0);
    // drain xw + h0 + all B; keep exactly the 8 h1 ops in flight
    asm volatile("s_waitcnt vmcnt(8) lgkmcnt(0)" ::: "memory");
    __builtin_amdgcn_sched_barrier(0);
    __builtin_amdgcn_s_barrier();        // h0 halves + xw published

    f32x4 acc[2][2];
    #pragma unroll
    for (int i = 0; i < 2; ++i)
        #pragma unroll
        for (int n = 0; n < 2; ++n) acc[i][n] = (f32x4){0.f, 0.f, 0.f, 0.f};

    auto compute = [&](int c, const uint4 (&bfr)[2][2]) {
        #pragma unroll
        for (int ks = 0; ks < 2; ++ks) {
            const int u = ks * 8 + sl * 2;
            bf16x8 af[2];
            #pragma unroll
            for (int i = 0; i < 2; ++i) {
                int row = i * 16 + r;
                const char* base = (const char*)As + row * 2048 + c * 256;
                float4 alo = *(const float4*)(base + ((u ^ (row & 15)) << 4));
                float4 ahi = *(const float4*)(base + (((u + 1) ^ (row & 15)) << 4));
                af[i] = cvt8(alo, ahi);
            }
            __builtin_amdgcn_s_setprio(1);
            #pragma unroll
            for (int i = 0; i < 2; ++i)
                #pragma unroll
                for (int nn = 0; nn < 2; ++nn)
                    acc[i][nn] = __builtin_amdgcn_mfma_f32_16x16x32_bf16(
                        af[i], *(const bf16x8*)&bfr[ks][nn], acc[i][nn], 0, 0, 0);
            __builtin_amdgcn_s_setprio(0);
        }
    };
    auto computeFeat = [&](const uint4 (&bfr)[2][2]) {
        #pragma unroll
        for (int ks = 0; ks < 2; ++ks) {
            bf16x8 af[2];
            #pragma unroll
            for (int i = 0; i < 2; ++i) {
                int row = i * 16 + r;
                const float* xp = &xw[ks][row + sl * 8];
                af[i] = cvt8(make_float4(xp[0], xp[1], xp[2], xp[3]),
                             make_float4(xp[4], xp[5], xp[6], xp[7]));
            }
            __builtin_amdgcn_s_setprio(1);
            #pragma unroll
            for (int i = 0; i < 2; ++i)
                #pragma unroll
                for (int nn = 0; nn < 2; ++nn)
                    acc[i][nn] = __builtin_amdgcn_mfma_f32_16x16x32_bf16(
                        af[i], *(const bf16x8*)&bfr[ks][nn], acc[i][nn], 0, 0, 0);
            __builtin_amdgcn_s_setprio(0);
        }
    };

    // ---- stage 1: chunks 0..3 + feat (h1 in flight underneath) ----
    compute(0, bA); compute(1, bB); compute(2, bC); compute(3, bD);
    computeFeat(bW);

    asm volatile("s_waitcnt vmcnt(0)" ::: "memory");
    __builtin_amdgcn_sched_barrier(0);
    __builtin_amdgcn_s_barrier();        // h1 halves published

    // ---- stage 2: chunks 4..7 (B re-loads L2-hot, compiler auto-waits) ----
    loadB(bA, 4); loadB(bB, 5); loadB(bC, 6); loadB(bD, 7);
    compute(4, bA); compute(5, bB); compute(6, bC); compute(7, bD);

    // ---- epilogue: + query, tanh, v-dot over this wave's 32 a-cols ----
    const float* qb = q + b * ATT;
    const float M = Mbuf[0];
    float pe[2][4];
    #pragma unroll
    for (int i = 0; i < 2; ++i)
        #pragma unroll
        for (int rr = 0; rr < 4; ++rr) pe[i][rr] = 0.f;
    #pragma unroll
    for (int nn = 0; nn < 2; ++nn) {
        int a = w * 32 + nn * 16 + r;
        float vvn = vw[a];
        float qvn = qb[a];
        #pragma unroll
        for (int i = 0; i < 2; ++i)
            #pragma unroll
            for (int rr = 0; rr < 4; ++rr)
                pe[i][rr] += vvn * fast_tanh(acc[i][nn][rr] + qvn);
    }
    #pragma unroll
    for (int m = 1; m < 16; m <<= 1)
        #pragma unroll
        for (int i = 0; i < 2; ++i)
            #pragma unroll
            for (int rr = 0; rr < 4; ++rr)
                pe[i][rr] += __shfl_xor(pe[i][rr], m, 64);
    if (r == 0) {
        #pragma unroll
        for (int i = 0; i < 2; ++i)
            #pragma unroll
            for (int rr = 0; rr < 4; ++rr)
                pequad[w][i * 16 + sl * 4 + rr] = pe[i][rr];
    }
    __syncthreads();
    if (tid < BT) {
        int t = t0 + tid;
        float e = pequad[0][tid] + pequad[1][tid] + pequad[2][tid] + pequad[3][tid];
        float v = 0.f;
        if (t < TT && !mask[b * TT + t]) v = __expf(e - M);
        if (t < TT) expE[b * TT + t] = v;
        sExp[tid] = v;
        float sv = v;
        #pragma unroll
        for (int off = 1; off < 32; off <<= 1) sv += __shfl_xor(sv, off, 64);
        if (tid == 0) ps[b * NTL + tile] = sv;
    }
    __syncthreads();

    // ---- fused ctx partial from the RESIDENT slab (no global re-read) ----
    {
        const int U   = tid >> 1;            // f32 unit of this thread's col pair
        const int sub = (tid & 1) * 8;
        float2 cacc = make_float2(0.f, 0.f);
        #pragma unroll 4
        for (int t = 0; t < BT; ++t) {
            float s = sExp[t];
            int byte = t * 2048 + (((U & ~15) | ((U ^ (t & 15)) & 15)) << 4) + sub;
            float2 v = *(const float2*)((const char*)As + byte);
            cacc.x += s * v.x; cacc.y += s * v.y;
        }
        *(float2*)&pctx[(size_t)(b * NTL + tile) * ENCD + tid * 2] = cacc;
    }

    // ---- last-block-per-b tail: cross-tile reduction (replaces 3rd kernel) ----
    __threadfence();                       // release: pctx/ps/expE visible agent-wide
    if (tid == 0) {
        int prev = __atomic_fetch_add(&cnt[b], 1, __ATOMIC_RELAXED);
        lastFlag = (prev == NTL - 1);
    }
    __syncthreads();
    if (lastFlag) {
        __threadfence();                   // acquire: see all tiles' writes
        float ssum = 0.f;
        #pragma unroll
        for (int i = 0; i < NTL; ++i) ssum += ps[b * NTL + i];
        float inv = 1.f / ssum;
        float2 a = make_float2(0.f, 0.f);
        #pragma unroll
        for (int i = 0; i < NTL; ++i) {
            float2 v = *(const float2*)&pctx[(size_t)(b * NTL + i) * ENCD + tid * 2];
            a.x += v.x; a.y += v.y;
        }
        a.x *= inv; a.y *= inv;
        *(float2*)&ctx[b * ENCD + tid * 2] = a;
        for (int t = tid; t < TT; t += 256)
            wout[b * TT + t] = expE[b * TT + t] * inv;
    }
}

// ---------------- launcher ----------------------------------------------------
extern "C" void kernel_launch(void* const* d_in, const int* in_sizes, int n_in,
                              void* d_out, int out_size, void* d_ws, size_t ws_size,
                              hipStream_t stream) {
    const float* dh   = (const float*)d_in[0];
    const float* enc  = (const float*)d_in[1];
    const float* pw   = (const float*)d_in[2];
    const float* pwc  = (const float*)d_in[3];
    const unsigned char* mask = (const unsigned char*)d_in[4];
    const float* cw   = (const float*)d_in[5];
    const float* lpw  = (const float*)d_in[6];
    const float* qw   = (const float*)d_in[7];
    const float* kw   = (const float*)d_in[8];
    const float* vw   = (const float*)d_in[9];

    float* out_ctx = (float*)d_out;                 // (64, 512)
    float* out_w   = out_ctx + BB * ENCD;           // (64, 1000)

    float* wsf    = (float*)d_ws;
    float*  q     = wsf;                                   // 8192
    float*  expE  = wsf + 8192;                            // 64000
    float*  ps    = wsf + 8192 + 64000;                    // 2048
    float*  pctx  = wsf + 8192 + 64000 + 2048;             // 64*32*512 = 1048576
    ushort* kwbF  = (ushort*)(wsf + 8192 + 64000 + 2048 + 1048576);  // 73728 bf16
    float*  Mbuf  = wsf + 8192 + 64000 + 2048 + 1048576 + 36864;     // 1
    int*    cnt   = (int*)(wsf + 8192 + 64000 + 2048 + 1048576 + 36864 + 16);  // 64

    k_prep    <<<dim3(101),     dim3(256), 0, stream>>>(kw, cw, lpw, dh, qw, vw, kwbF, q, Mbuf, cnt);
    k_energies<<<dim3(BB, NTL), dim3(256), 0, stream>>>(enc, pw, pwc, mask, kwbF, vw, q, Mbuf,
                                                        expE, pctx, ps, cnt, out_ctx, out_w);
}

// Round 21
// 63.856 us; speedup vs baseline: 3.3863x; 3.3863x over previous
//
#include <hip/hip_runtime.h>
#include <hip/hip_bf16.h>
#include <math.h>

#define BB   64
#define TT   1000
#define DEC  1024
#define ENCD 512
#define ATT  128
#define FILT 32
#define KSZ  31
#define PADW 15
#define BT   32    // t-tile per block (full-K slab resident)
#define NTL  32    // tiles per b
#define XWN  64    // x-window alloc (62 used)

typedef __attribute__((ext_vector_type(8))) short bf16x8;
typedef __attribute__((ext_vector_type(4))) float f32x4;

static __device__ __forceinline__ ushort f2bf(float f) {
    union { float f; unsigned u; } v; v.f = f;
    unsigned r = (v.u + 0x7FFFu + ((v.u >> 16) & 1u)) >> 16;   // RNE
    return (ushort)r;
}

static __device__ __forceinline__ bf16x8 cvt8(float4 lo, float4 hi) {
    union { __hip_bfloat162 h[4]; bf16x8 v; } u;
    u.h[0] = __float22bfloat162_rn(make_float2(lo.x, lo.y));
    u.h[1] = __float22bfloat162_rn(make_float2(lo.z, lo.w));
    u.h[2] = __float22bfloat162_rn(make_float2(hi.x, hi.y));
    u.h[3] = __float22bfloat162_rn(make_float2(hi.z, hi.w));
    return u.v;
}

static __device__ __forceinline__ float fast_tanh(float x) {
    float e = __expf(2.f * x);
    return 1.f - 2.f * __builtin_amdgcn_rcpf(e + 1.f);
}

// async global->LDS, 16B per lane; LDS dest = wave-uniform base + lane*16
static __device__ __forceinline__ void gl2lds16(const void* g, void* l) {
    __builtin_amdgcn_global_load_lds(
        (const __attribute__((address_space(1))) unsigned*)g,
        (__attribute__((address_space(3))) unsigned*)l, 16, 0, 0);
}

// ---------------- K0: pack key_w + W2 (frag-major), M = sum|v|, query GEMV ----
__global__ __launch_bounds__(256) void k_prep(const float* __restrict__ kw,
                                              const float* __restrict__ cw,
                                              const float* __restrict__ lpw,
                                              const float* __restrict__ dh,
                                              const float* __restrict__ qw,
                                              const float* __restrict__ vw,
                                              ushort* __restrict__ kwbF,
                                              float* __restrict__ q,
                                              float* __restrict__ Mbuf) {
    __shared__ float qred[128];
    if (blockIdx.x < 32) {
        int idx = blockIdx.x * 256 + threadIdx.x;     // 0..8191
        int l  = idx & 63;
        int n  = (idx >> 6) & 7;
        int ks = (idx >> 9) & 1;
        int c  = idx >> 10;
        int a  = n * 16 + (l & 15);
        int k0 = c * 64 + ks * 32 + (l >> 4) * 8;
        ushort u[8];
        #pragma unroll
        for (int j = 0; j < 8; ++j) u[j] = f2bf(kw[a * ENCD + k0 + j]);
        *(uint4*)&kwbF[(size_t)idx * 8] = *(const uint4*)u;
    } else if (blockIdx.x < 36) {
        // W2[c][k][a] = sum_f conv_w[f][c][k] * loc_proj_w[a][f];  k==31 row = 0
        int idx = (blockIdx.x - 32) * 256 + threadIdx.x;   // 0..1023
        int l  = idx & 63;
        int n  = (idx >> 6) & 7;
        int ks = (idx >> 9) & 1;                      // conv input channel
        int a  = n * 16 + (l & 15);
        int s  = l >> 4;
        ushort u[8];
        #pragma unroll
        for (int j = 0; j < 8; ++j) {
            int k = s * 8 + j;
            float v = 0.f;
            if (k < KSZ) {
                #pragma unroll
                for (int f = 0; f < FILT; ++f)
                    v += cw[(f * 2 + ks) * KSZ + k] * lpw[a * FILT + f];
            }
            u[j] = f2bf(v);
        }
        *(uint4*)&kwbF[(size_t)(((16 + ks) * 8 + n) * 64 + l) * 8] = *(const uint4*)u;
    } else if (blockIdx.x == 36) {
        if (threadIdx.x < 64) {
            float m0 = fabsf(vw[threadIdx.x]) + fabsf(vw[threadIdx.x + 64]);
            #pragma unroll
            for (int off = 1; off < 64; off <<= 1) m0 += __shfl_xor(m0, off, 64);
            if (threadIdx.x == 0) Mbuf[0] = m0;
        }
    } else {
        // query GEMV, one block per b, 128 a x 2-way k-split
        int b  = blockIdx.x - 37;
        int a  = threadIdx.x & 127;
        int kh = threadIdx.x >> 7;
        const float* dhb = dh + b * DEC + kh * 512;
        const float* qwa = qw + a * DEC + kh * 512;
        float s = 0.f;
        #pragma unroll 4
        for (int k = 0; k < 512; k += 4) {
            float4 x = *(const float4*)&dhb[k];
            float4 w = *(const float4*)&qwa[k];
            s += x.x * w.x + x.y * w.y + x.z * w.z + x.w * w.w;
        }
        if (kh == 1) qred[a] = s;
        __syncthreads();
        if (kh == 0) q[b * ATT + a] = s + qred[a];
    }
}

// ------- K3: contiguous-stream slab GEMM K=576 -> expE + ctx from LDS ---------
// BT=32 rows, full-K f32 slab As[32][512] (64 KB, 2 blocks/CU). Each wave
// gl2lds-streams 8 whole rows (contiguous 1 KB per op; per-lane source
// pre-swizzled ^(row&15) within 256B groups). Two stages: chunks 0-3+feat
// compute under the in-flight second row-halves (vmcnt(8)); then 4-7.
// 4-way a-split; B frag-major -> named reg sets. enc HBM-read exactly once.
__global__ __launch_bounds__(256) void k_energies(
    const float* __restrict__ enc, const float* __restrict__ pw,
    const float* __restrict__ pwc, const unsigned char* __restrict__ mask,
    const ushort* __restrict__ kwbF, const float* __restrict__ vw,
    const float* __restrict__ q, const float* __restrict__ Mbuf,
    float* __restrict__ expE, float* __restrict__ pctx,
    float* __restrict__ ps)
{
    __shared__ __align__(16) float As[BT * ENCD];   // 64 KB slab, unit-swizzled
    __shared__ __align__(16) float xw[2][XWN];
    __shared__ float pequad[4][BT];
    __shared__ float sExp[BT];

    const int b    = blockIdx.x;
    const int tile = blockIdx.y;
    const int t0   = tile * BT;
    const int tid  = threadIdx.x;
    const int w    = tid >> 6;       // 4 waves; wave owns a-cols [w*32, w*32+32)
    const int l    = tid & 63;
    const int r    = l & 15;
    const int sl   = l >> 4;

    const float* encb = enc + (size_t)b * TT * ENCD;

    // ---- xw staging FIRST (oldest VMEM ops; waves 2,3 have none) ----
    for (int i = tid; i < 2 * XWN; i += 256) {
        int c  = i / XWN;
        int ii = i - c * XWN;
        int tg = t0 + ii - PADW;
        const float* src = c ? pwc : pw;
        xw[c][ii] = (ii < BT + KSZ - 1 && tg >= 0 && tg < TT) ? src[b * TT + tg] : 0.f;
    }
    __builtin_amdgcn_sched_barrier(0);

    // ---- h0: first halves of this wave's 8 rows (contiguous 1 KB streams) ----
    #pragma unroll
    for (int j = 0; j < 8; ++j) {
        int rl = w * 8 + j;
        int rg = t0 + rl; if (rg >= TT) rg = TT - 1;
        const float* src = encb + (size_t)rg * ENCD + (size_t)(sl * 16 + (r ^ (rl & 15))) * 4;
        gl2lds16(src, (char*)As + rl * 2048);
    }
    __builtin_amdgcn_sched_barrier(0);

    // ---- B for stage 1 (chunks 0..3 + feat 8) -> named reg sets ----
    uint4 bA[2][2], bB[2][2], bC[2][2], bD[2][2], bW[2][2];
    auto loadB = [&](uint4 (&dst)[2][2], int c) {
        #pragma unroll
        for (int ks = 0; ks < 2; ++ks)
            #pragma unroll
            for (int nn = 0; nn < 2; ++nn)
                dst[ks][nn] = *(const uint4*)&kwbF[(size_t)(((c * 2 + ks) * 8 + w * 2 + nn) * 64 + l) * 8];
    };
    loadB(bA, 0); loadB(bB, 1); loadB(bC, 2); loadB(bD, 3); loadB(bW, 8);
    __builtin_amdgcn_sched_barrier(0);

    // ---- h1: second halves (stay in flight across stage 1) ----
    #pragma unroll
    for (int j = 0; j < 8; ++j) {
        int rl = w * 8 + j;
        int rg = t0 + rl; if (rg >= TT) rg = TT - 1;
        const float* src = encb + (size_t)rg * ENCD + 256 + (size_t)(sl * 16 + (r ^ (rl & 15))) * 4;
        gl2lds16(src, (char*)As + rl * 2048 + 1024);
    }
    __builtin_amdgcn_sched_barrier(0);
    // drain xw + h0 + all B; keep exactly the 8 h1 ops in flight
    asm volatile("s_waitcnt vmcnt(8) lgkmcnt(0)" ::: "memory");
    __builtin_amdgcn_sched_barrier(0);
    __builtin_amdgcn_s_barrier();        // h0 halves + xw published

    f32x4 acc[2][2];
    #pragma unroll
    for (int i = 0; i < 2; ++i)
        #pragma unroll
        for (int n = 0; n < 2; ++n) acc[i][n] = (f32x4){0.f, 0.f, 0.f, 0.f};

    // A fragment: global unit U = c*16 + ks*8 + sl*2 (+1); stored at
    // byte = row*2048 + c*256 + (((ks*8+sl*2) ^ (row&15)) << 4)
    auto compute = [&](int c, const uint4 (&bfr)[2][2]) {
        #pragma unroll
        for (int ks = 0; ks < 2; ++ks) {
            const int u = ks * 8 + sl * 2;
            bf16x8 af[2];
            #pragma unroll
            for (int i = 0; i < 2; ++i) {
                int row = i * 16 + r;
                const char* base = (const char*)As + row * 2048 + c * 256;
                float4 alo = *(const float4*)(base + ((u ^ (row & 15)) << 4));
                float4 ahi = *(const float4*)(base + (((u + 1) ^ (row & 15)) << 4));
                af[i] = cvt8(alo, ahi);
            }
            __builtin_amdgcn_s_setprio(1);
            #pragma unroll
            for (int i = 0; i < 2; ++i)
                #pragma unroll
                for (int nn = 0; nn < 2; ++nn)
                    acc[i][nn] = __builtin_amdgcn_mfma_f32_16x16x32_bf16(
                        af[i], *(const bf16x8*)&bfr[ks][nn], acc[i][nn], 0, 0, 0);
            __builtin_amdgcn_s_setprio(0);
        }
    };
    auto computeFeat = [&](const uint4 (&bfr)[2][2]) {
        #pragma unroll
        for (int ks = 0; ks < 2; ++ks) {
            bf16x8 af[2];
            #pragma unroll
            for (int i = 0; i < 2; ++i) {
                int row = i * 16 + r;
                const float* xp = &xw[ks][row + sl * 8];
                af[i] = cvt8(make_float4(xp[0], xp[1], xp[2], xp[3]),
                             make_float4(xp[4], xp[5], xp[6], xp[7]));
            }
            __builtin_amdgcn_s_setprio(1);
            #pragma unroll
            for (int i = 0; i < 2; ++i)
                #pragma unroll
                for (int nn = 0; nn < 2; ++nn)
                    acc[i][nn] = __builtin_amdgcn_mfma_f32_16x16x32_bf16(
                        af[i], *(const bf16x8*)&bfr[ks][nn], acc[i][nn], 0, 0, 0);
            __builtin_amdgcn_s_setprio(0);
        }
    };

    // ---- stage 1: chunks 0..3 + feat (h1 in flight underneath) ----
    compute(0, bA); compute(1, bB); compute(2, bC); compute(3, bD);
    computeFeat(bW);

    asm volatile("s_waitcnt vmcnt(0)" ::: "memory");
    __builtin_amdgcn_sched_barrier(0);
    __builtin_amdgcn_s_barrier();        // h1 halves published

    // ---- stage 2: chunks 4..7 (B re-loads L2-hot, compiler auto-waits) ----
    loadB(bA, 4); loadB(bB, 5); loadB(bC, 6); loadB(bD, 7);
    compute(4, bA); compute(5, bB); compute(6, bC); compute(7, bD);

    // ---- epilogue: + query, tanh, v-dot over this wave's 32 a-cols ----
    const float* qb = q + b * ATT;
    const float M = Mbuf[0];
    float pe[2][4];
    #pragma unroll
    for (int i = 0; i < 2; ++i)
        #pragma unroll
        for (int rr = 0; rr < 4; ++rr) pe[i][rr] = 0.f;
    #pragma unroll
    for (int nn = 0; nn < 2; ++nn) {
        int a = w * 32 + nn * 16 + r;
        float vvn = vw[a];
        float qvn = qb[a];
        #pragma unroll
        for (int i = 0; i < 2; ++i)
            #pragma unroll
            for (int rr = 0; rr < 4; ++rr)
                pe[i][rr] += vvn * fast_tanh(acc[i][nn][rr] + qvn);
    }
    #pragma unroll
    for (int m = 1; m < 16; m <<= 1)
        #pragma unroll
        for (int i = 0; i < 2; ++i)
            #pragma unroll
            for (int rr = 0; rr < 4; ++rr)
                pe[i][rr] += __shfl_xor(pe[i][rr], m, 64);
    if (r == 0) {
        #pragma unroll
        for (int i = 0; i < 2; ++i)
            #pragma unroll
            for (int rr = 0; rr < 4; ++rr)
                pequad[w][i * 16 + sl * 4 + rr] = pe[i][rr];
    }
    __syncthreads();
    if (tid < BT) {
        int t = t0 + tid;
        float e = pequad[0][tid] + pequad[1][tid] + pequad[2][tid] + pequad[3][tid];
        float v = 0.f;
        if (t < TT && !mask[b * TT + t]) v = __expf(e - M);
        if (t < TT) expE[b * TT + t] = v;
        sExp[tid] = v;
        float sv = v;
        #pragma unroll
        for (int off = 1; off < 32; off <<= 1) sv += __shfl_xor(sv, off, 64);
        if (tid == 0) ps[b * NTL + tile] = sv;
    }
    __syncthreads();

    // ---- fused ctx partial from the RESIDENT slab (no global re-read) ----
    {
        const int U   = tid >> 1;            // f32 unit of this thread's col pair
        const int sub = (tid & 1) * 8;
        float2 cacc = make_float2(0.f, 0.f);
        #pragma unroll 4
        for (int t = 0; t < BT; ++t) {
            float s = sExp[t];
            int byte = t * 2048 + (((U & ~15) | ((U ^ (t & 15)) & 15)) << 4) + sub;
            float2 v = *(const float2*)((const char*)As + byte);
            cacc.x += s * v.x; cacc.y += s * v.y;
        }
        *(float2*)&pctx[(size_t)(b * NTL + tile) * ENCD + tid * 2] = cacc;
    }
}

// -------- K6: reduce 32 partials -> context + attention weights (128 blocks) --
__global__ __launch_bounds__(256) void k_ctx_reduce(const float* __restrict__ pctx,
                                                    const float* __restrict__ ps,
                                                    const float* __restrict__ expE,
                                                    float* __restrict__ ctx,
                                                    float* __restrict__ wout) {
    int bid = blockIdx.x, tid = threadIdx.x;
    __shared__ float sps[NTL];
    int b = (bid < BB) ? bid : (bid - BB);
    if (tid < NTL) sps[tid] = ps[b * NTL + tid];
    __syncthreads();
    float s = 0.f;
    #pragma unroll
    for (int i = 0; i < NTL; ++i) s += sps[i];
    float inv = 1.f / s;
    if (bid < BB) {
        float2 a = make_float2(0.f, 0.f);
        #pragma unroll
        for (int i = 0; i < NTL; ++i) {
            float2 v = *(const float2*)&pctx[(size_t)(b * NTL + i) * ENCD + tid * 2];
            a.x += v.x; a.y += v.y;
        }
        a.x *= inv; a.y *= inv;
        *(float2*)&ctx[b * ENCD + tid * 2] = a;
    } else {
        for (int t = tid; t < TT; t += 256)
            wout[b * TT + t] = expE[b * TT + t] * inv;
    }
}

// ---------------- launcher ----------------------------------------------------
extern "C" void kernel_launch(void* const* d_in, const int* in_sizes, int n_in,
                              void* d_out, int out_size, void* d_ws, size_t ws_size,
                              hipStream_t stream) {
    const float* dh   = (const float*)d_in[0];
    const float* enc  = (const float*)d_in[1];
    const float* pw   = (const float*)d_in[2];
    const float* pwc  = (const float*)d_in[3];
    const unsigned char* mask = (const unsigned char*)d_in[4];
    const float* cw   = (const float*)d_in[5];
    const float* lpw  = (const float*)d_in[6];
    const float* qw   = (const float*)d_in[7];
    const float* kw   = (const float*)d_in[8];
    const float* vw   = (const float*)d_in[9];

    float* out_ctx = (float*)d_out;                 // (64, 512)
    float* out_w   = out_ctx + BB * ENCD;           // (64, 1000)

    float* wsf    = (float*)d_ws;
    float*  q     = wsf;                                   // 8192
    float*  expE  = wsf + 8192;                            // 64000
    float*  ps    = wsf + 8192 + 64000;                    // 2048
    float*  pctx  = wsf + 8192 + 64000 + 2048;             // 64*32*512 = 1048576
    ushort* kwbF  = (ushort*)(wsf + 8192 + 64000 + 2048 + 1048576);  // 73728 bf16
    float*  Mbuf  = wsf + 8192 + 64000 + 2048 + 1048576 + 36864;     // 1

    k_prep    <<<dim3(101),     dim3(256), 0, stream>>>(kw, cw, lpw, dh, qw, vw, kwbF, q, Mbuf);
    k_energies<<<dim3(BB, NTL), dim3(256), 0, stream>>>(enc, pw, pwc, mask, kwbF, vw, q, Mbuf, expE, pctx, ps);
    k_ctx_reduce <<<dim3(128),  dim3(256), 0, stream>>>(pctx, ps, expE, out_ctx, out_w);
}